// Round 2
// 763.138 us; speedup vs baseline: 1.4133x; 1.4133x over previous
//
#include <hip/hip_runtime.h>

// ---------------------------------------------------------------------------
// TABL: X1 = W1@X[b]; E = X1@W; A = softmax over batch axis;
// tem = X1*(alpha*A + 1-alpha); Y = tem@W2 + bias.
// Batch-persistent blocks, STATIC LDS <= 64KB (dynamic >64KB is unproven on
// this harness). W1 fragments + alpha/S + bias live in registers. ph1:
// S[p,s] = sum_b exp(W1@(X@W)). ph2: per batch GEMM1 -> GEMM2 -> gate ->
// GEMM3 with a Wt/W2t swap buffer (register-staged async copies).
// bf16 MFMA 16x16x32, fp32 accumulate.
// ---------------------------------------------------------------------------

typedef __attribute__((ext_vector_type(8))) short short8;   // 8 bf16 = 4 VGPR
typedef __attribute__((ext_vector_type(4))) float floatx4;  // MFMA C/D

constexpr int Bb = 8192;

// LDS operand layouts (bf16 elems). A-store[m][k] / B-store[n][k], row-major.
// K(t)=100 padded to 128, stride 136 shorts (68 words == 4 mod 32, 2-way free).
// K(d)=40  padded to 64,  stride 72  shorts (36 words == 4 mod 32).
constexpr int ST1 = 136;
constexpr int ST2 = 72;

constexpr int XB_B   = 48  * ST1 * 2;  // 13056  A: X[d][t]        (ph1)
constexpr int XWT_B  = 112 * ST2 * 2;  // 16128  B: XW^T[s][d]     (ph1)
constexpr int WT_B   = 112 * ST1 * 2;  // 30464  B: W^T[s][t]
constexpr int W2T_B  = 112 * ST1 * 2;  // 30464  B: W2^T[q][t]
constexpr int XT_B   = 112 * ST2 * 2;  // 16128  B: X^T[t][d]      (ph2)
constexpr int X1A_B  = 128 * ST1 * 2;  // 34816  A: X1/tem[p][t]   (ph2)

// ws layout (bytes): S fp32[12000] @0; then prepped bf16 weights.
constexpr int WS_S_BYTES = 48000;
constexpr int WTG_OFF  = 48000;
constexpr int W1G_OFF  = WTG_OFF + WT_B;     // 78464  [128][ST2] W1[p][d]
constexpr int W2TG_OFF = W1G_OFF + 128 * ST2 * 2;  // 96896

// ph1 static LDS: Xb @0, XWt @13056, Wt @29184 -> 59648 B (2 blocks/CU).
constexpr int P1_XB  = 0;
constexpr int P1_XWT = XB_B;               // 13056
constexpr int P1_WT  = P1_XWT + XWT_B;     // 29184
constexpr int P1_LDS = P1_WT + WT_B;       // 59648

// ph2 static LDS: region A @0 (Xt aliased into X1A head), Wbuf @34816.
constexpr int P2_WB  = X1A_B;              // 34816
constexpr int P2_LDS = P2_WB + WT_B;       // 65280 (fits 64KB static)

constexpr int NB1 = 16;   // batches per ph1 block -> grid 512 (2 blocks/CU)
constexpr int NB2 = 32;   // batches per ph2 block -> grid 256 (1 block/CU)

constexpr int WCHUNKS = WT_B / 16;         // 1904 int4 per W swap copy

__device__ __forceinline__ unsigned short f2bf(float f) {
  union { float f; unsigned u; } v; v.f = f;
  return (unsigned short)((v.u + 0x7FFFu + ((v.u >> 16) & 1u)) >> 16);
}

__device__ __forceinline__ void copy16(void* dst, const void* src, int nbytes,
                                       int tid, int nthr) {
  int4* d = (int4*)dst; const int4* s = (const int4*)src;
  const int n = nbytes >> 4;
  for (int i = tid; i < n; i += nthr) d[i] = s[i];
}

// ---------------------------------------------------------------------------
// Prep: convert W, W1, W2 to zero-padded bf16 operand layouts in ws.
// ---------------------------------------------------------------------------
__global__ void tabl_prep(const float* __restrict__ W1, const float* __restrict__ W,
                          const float* __restrict__ W2, char* ws) {
  int i = blockIdx.x * 256 + threadIdx.x;
  if (i < 112 * ST1) {                         // W^T[s][t]
    int s = i / ST1, t = i % ST1;
    ((unsigned short*)(ws + WTG_OFF))[i] = (s < 100 && t < 100) ? f2bf(W[t * 100 + s]) : 0;
  } else if (i < 112 * ST1 + 128 * ST2) {      // W1[p][d]
    int j = i - 112 * ST1;
    int p = j / ST2, d = j % ST2;
    ((unsigned short*)(ws + W1G_OFF))[j] = (p < 120 && d < 40) ? f2bf(W1[p * 40 + d]) : 0;
  } else if (i < 112 * ST1 + 128 * ST2 + 112 * ST1) {  // W2^T[q][t]
    int j = i - 112 * ST1 - 128 * ST2;
    int q = j / ST1, t = j % ST1;
    ((unsigned short*)(ws + W2TG_OFF))[j] = (q < 100 && t < 100) ? f2bf(W2[t * 100 + q]) : 0;
  }
}

// ---------------------------------------------------------------------------
// Phase 1: S[p,s] += exp(E[b,p,s]) for NB1 batches/block. Wt resident, W1 in
// regs. Per batch: [barrier] XW=X@W -> XWt stores -> [barrier] E=W1@XW +
// exp-accumulate -> stage next Xb (prefetched into regs under XW GEMM).
// ---------------------------------------------------------------------------
__global__ __launch_bounds__(256, 2)
void tabl_ph1(const float* __restrict__ X, const char* __restrict__ ws,
              float* __restrict__ S) {
  __shared__ __align__(16) char smem[P1_LDS];
  short* Xb  = (short*)(smem + P1_XB);
  short* XWt = (short*)(smem + P1_XWT);
  short* Wt  = (short*)(smem + P1_WT);

  const int tid = threadIdx.x;
  const int wid = tid >> 6, lane = tid & 63;
  const int quad = lane >> 4, r = lane & 15;
  const floatx4 zed = {0.f, 0.f, 0.f, 0.f};

  // W1 A-fragments for this wave's two p-tiles {2*wid, 2*wid+1}, from ws.
  short8 w1f[2][2];
#pragma unroll
  for (int h = 0; h < 2; ++h)
#pragma unroll
    for (int ks = 0; ks < 2; ++ks)
      w1f[h][ks] = *(const short8*)(ws + W1G_OFF +
          2 * (((2 * wid + h) * 16 + r) * ST2 + ks * 32 + quad * 8));

  // Resident staging + pad zeroing (once per block).
  copy16(Wt, ws + WTG_OFF, WT_B, tid, 256);
  for (int i = tid; i < 8 * ST1; i += 256) {            // Xb rows d in [40,48)
    int dd = 40 + i / ST1, tt = i % ST1; Xb[dd * ST1 + tt] = 0;
  }
  for (int i = tid; i < 40 * 28; i += 256) {            // Xb cols t in [100,128)
    int dd = i / 28, tt = 100 + i % 28; Xb[dd * ST1 + tt] = 0;
  }
  for (int i = tid; i < 112 * 16; i += 256) {           // XWt cols d in [48,64)
    int rr = i / 16, cc = 48 + i % 16; XWt[rr * ST2 + cc] = 0;
  }

  const int b0 = blockIdx.x * NB1;
  {  // prologue: stage X(b0) into Xb (A-layout X[d][t])
    const float4* x4 = (const float4*)(X + (size_t)b0 * 4000);
#pragma unroll
    for (int k = 0; k < 4; ++k) {
      int idx = tid + k * 256;
      if (idx < 1000) {
        float4 v = x4[idx];
        short4 pk; pk.x = (short)f2bf(v.x); pk.y = (short)f2bf(v.y);
        pk.z = (short)f2bf(v.z); pk.w = (short)f2bf(v.w);
        int e0 = idx * 4, d = e0 / 100, t = e0 - d * 100;
        *(short4*)&Xb[d * ST1 + t] = pk;
      }
    }
  }

  floatx4 sacc[2][7];
#pragma unroll
  for (int h = 0; h < 2; ++h)
#pragma unroll
    for (int n = 0; n < 7; ++n) sacc[h][n] = zed;

  for (int nb = 0; nb < NB1; ++nb) {
    __syncthreads();  // Xb(nb) ready; prev batch's XWt reads retired

    // prefetch next batch's X into regs (lands during the GEMMs below)
    float4 xr[4];
    const bool pf = (nb + 1 < NB1);
    if (pf) {
      const float4* x4n = (const float4*)(X + (size_t)(b0 + nb + 1) * 4000);
#pragma unroll
      for (int k = 0; k < 4; ++k) {
        int idx = tid + k * 256;
        if (idx < 1000) xr[k] = x4n[idx];
      }
    }

    // XW = X@W : M=d(3 tiles), N=s(wave ni in {wid, wid+4}), K=t(4 steps)
    floatx4 xw[2][3];
#pragma unroll
    for (int ns = 0; ns < 2; ++ns)
#pragma unroll
      for (int m = 0; m < 3; ++m) xw[ns][m] = zed;
#pragma unroll
    for (int ks = 0; ks < 4; ++ks) {
      short8 a0 = *(const short8*)&Xb[(0 * 16 + r) * ST1 + ks * 32 + quad * 8];
      short8 a1 = *(const short8*)&Xb[(1 * 16 + r) * ST1 + ks * 32 + quad * 8];
      short8 a2 = *(const short8*)&Xb[(2 * 16 + r) * ST1 + ks * 32 + quad * 8];
#pragma unroll
      for (int ns = 0; ns < 2; ++ns) {
        int ni = wid + ns * 4;
        if (ni < 7) {
          short8 bf = *(const short8*)&Wt[(ni * 16 + r) * ST1 + ks * 32 + quad * 8];
          xw[ns][0] = __builtin_amdgcn_mfma_f32_16x16x32_bf16(a0, bf, xw[ns][0], 0, 0, 0);
          xw[ns][1] = __builtin_amdgcn_mfma_f32_16x16x32_bf16(a1, bf, xw[ns][1], 0, 0, 0);
          xw[ns][2] = __builtin_amdgcn_mfma_f32_16x16x32_bf16(a2, bf, xw[ns][2], 0, 0, 0);
        }
      }
    }
    // store D[d][s] -> XWt[s][d] (4 consecutive d packed per 8B store)
#pragma unroll
    for (int ns = 0; ns < 2; ++ns) {
      int ni = wid + ns * 4;
      if (ni < 7) {
#pragma unroll
        for (int m = 0; m < 3; ++m) {
          short4 pk;
          pk.x = (short)f2bf(xw[ns][m][0]); pk.y = (short)f2bf(xw[ns][m][1]);
          pk.z = (short)f2bf(xw[ns][m][2]); pk.w = (short)f2bf(xw[ns][m][3]);
          *(short4*)&XWt[(ni * 16 + r) * ST2 + m * 16 + quad * 4] = pk;
        }
      }
    }
    __syncthreads();  // XWt ready; all Xb reads retired

    // E = W1@XW : wave mi in {2*wid, 2*wid+1}; per-n e regs, exp-accumulate
#pragma unroll
    for (int n = 0; n < 7; ++n) {
      floatx4 e0 = zed, e1 = zed;
#pragma unroll
      for (int ks = 0; ks < 2; ++ks) {
        short8 bf = *(const short8*)&XWt[(n * 16 + r) * ST2 + ks * 32 + quad * 8];
        e0 = __builtin_amdgcn_mfma_f32_16x16x32_bf16(w1f[0][ks], bf, e0, 0, 0, 0);
        e1 = __builtin_amdgcn_mfma_f32_16x16x32_bf16(w1f[1][ks], bf, e1, 0, 0, 0);
      }
#pragma unroll
      for (int c = 0; c < 4; ++c) {
        sacc[0][n][c] += __expf(e0[c]);
        sacc[1][n][c] += __expf(e1[c]);
      }
    }

    // stage next Xb (Xb reads retired at the barrier above; disjoint from XWt)
    if (pf) {
#pragma unroll
      for (int k = 0; k < 4; ++k) {
        int idx = tid + k * 256;
        if (idx < 1000) {
          short4 pk; pk.x = (short)f2bf(xr[k].x); pk.y = (short)f2bf(xr[k].y);
          pk.z = (short)f2bf(xr[k].z); pk.w = (short)f2bf(xr[k].w);
          int e0 = idx * 4, d = e0 / 100, t = e0 - d * 100;
          *(short4*)&Xb[d * ST1 + t] = pk;
        }
      }
    }
  }

#pragma unroll
  for (int h = 0; h < 2; ++h) {
    int mi = 2 * wid + h;
#pragma unroll
    for (int n = 0; n < 7; ++n) {
      int s = n * 16 + r;
#pragma unroll
      for (int c = 0; c < 4; ++c) {
        int p = mi * 16 + quad * 4 + c;
        if (p < 120 && s < 100) atomicAdd(&S[p * 100 + s], sacc[h][n][c]);
      }
    }
  }
}

// ---------------------------------------------------------------------------
// Phase 2: NB2 batches/block, 8 waves (512 thr), 1 block/CU. Regions:
// A @0: Xt (16128, aliased) then X1A/temA (34816); Wbuf @34816 (Wt or W2t).
// Wave mapping: mp = wid&3 -> p-tiles {2mp, 2mp+1}; nh = wid>>2 -> n-tiles
// [nh*4, nh*4+NJ). W1 frags + alpha/S + bias in registers. 6 barriers/batch;
// W swap copies are register-staged one phase early (latency hides under MFMA).
// ---------------------------------------------------------------------------
__global__ __launch_bounds__(512, 2)
void tabl_ph2(const float* __restrict__ X, const char* __restrict__ ws,
              const float* __restrict__ alphap, const float* __restrict__ bias,
              float* __restrict__ Y) {
  __shared__ __align__(16) char smem[P2_LDS];
  short* Xt   = (short*)(smem);            // [112][ST2], aliases X1A head
  short* X1A  = (short*)(smem);            // [128][ST1]
  short* Wbuf = (short*)(smem + P2_WB);    // [112][ST1], Wt or W2t
  const float* S = (const float*)ws;

  const int tid = threadIdx.x;
  const int wid = tid >> 6, lane = tid & 63;
  const int quad = lane >> 4, r = lane & 15;
  const int mp = wid & 3, nh = wid >> 2;
  const int NJ = nh ? 3 : 4;
  const floatx4 zed = {0.f, 0.f, 0.f, 0.f};
  const int4 iz = {0, 0, 0, 0};

  const int b0 = blockIdx.x * NB2;
  const float alpha = alphap[0];
  const float oma = 1.f - alpha;

  // Per-lane constants, fixed across all batches of this block.
  floatx4 sinv[2][4], br[2][4];
#pragma unroll
  for (int h = 0; h < 2; ++h)
#pragma unroll
    for (int j = 0; j < 4; ++j) {
      int n = nh * 4 + j;
      int s = n * 16 + r;
#pragma unroll
      for (int c = 0; c < 4; ++c) {
        int p = (2 * mp + h) * 16 + quad * 4 + c;
        bool ok = (j < NJ) && (p < 120) && (s < 100);
        sinv[h][j][c] = ok ? alpha / S[p * 100 + s] : 0.f;
        br[h][j][c]   = ok ? bias[p * 100 + s] : 0.f;
      }
    }

  // W1 B... A-fragments (GEMM1 A-operand) for p-tiles {2mp, 2mp+1}.
  short8 w1f[2][2];
#pragma unroll
  for (int h = 0; h < 2; ++h)
#pragma unroll
    for (int ks = 0; ks < 2; ++ks)
      w1f[h][ks] = *(const short8*)(ws + W1G_OFF +
          2 * (((2 * mp + h) * 16 + r) * ST2 + ks * 32 + quad * 8));

  // Init: Wbuf <- Wt; Xt pads + data for batch b0.
  copy16(Wbuf, ws + WTG_OFF, WT_B, tid, 512);
  if (tid < 108) ((int4*)Xt)[900 + tid] = iz;            // Xt rows t in [100,112)
  for (int z = tid; z < 300; z += 512) {                 // Xt cols d in [40,64)
    int t = z / 3, u = z - 3 * t;
    ((int4*)Xt)[t * 9 + 5 + u] = iz;
  }
  {
    const float4* x4 = (const float4*)(X + (size_t)b0 * 4000);
#pragma unroll
    for (int k = 0; k < 2; ++k) {
      int idx = tid + k * 512;
      if (idx < 1000) {
        float4 v = x4[idx];
        int e0 = idx * 4, d = e0 / 100, t0 = e0 - d * 100;
        Xt[(t0 + 0) * ST2 + d] = (short)f2bf(v.x);
        Xt[(t0 + 1) * ST2 + d] = (short)f2bf(v.y);
        Xt[(t0 + 2) * ST2 + d] = (short)f2bf(v.z);
        Xt[(t0 + 3) * ST2 + d] = (short)f2bf(v.w);
      }
    }
  }

  for (int i = 0; i < NB2; ++i) {
    __syncthreads();  // (a) Xt + Wbuf(Wt) ready; prev temA reads retired

    // prefetch next batch's X into regs (consumed in phase f)
    float4 xr[2];
    const bool pf = (i + 1 < NB2);
    if (pf) {
      const float4* x4n = (const float4*)(X + (size_t)(b0 + i + 1) * 4000);
#pragma unroll
      for (int k = 0; k < 2; ++k) {
        int idx = tid + k * 512;
        if (idx < 1000) xr[k] = x4n[idx];
      }
    }

    // GEMM1: X1 = W1@X  (A=w1f regs, B=Xt[t][d], K=d 2 steps)
    floatx4 x1[2][4];
#pragma unroll
    for (int h = 0; h < 2; ++h)
#pragma unroll
      for (int j = 0; j < 4; ++j) x1[h][j] = zed;
#pragma unroll
    for (int j = 0; j < 4; ++j) {
      if (j < NJ) {
        int n = nh * 4 + j;
#pragma unroll
        for (int ks = 0; ks < 2; ++ks) {
          short8 bf = *(const short8*)&Xt[(n * 16 + r) * ST2 + ks * 32 + quad * 8];
          x1[0][j] = __builtin_amdgcn_mfma_f32_16x16x32_bf16(w1f[0][ks], bf, x1[0][j], 0, 0, 0);
          x1[1][j] = __builtin_amdgcn_mfma_f32_16x16x32_bf16(w1f[1][ks], bf, x1[1][j], 0, 0, 0);
        }
      }
    }
    __syncthreads();  // (b) Xt reads retired; region A free for X1A stores

    // issue W2t -> regs (consumed after barrier (d); lands during GEMM2)
    int4 wreg[4];
#pragma unroll
    for (int k = 0; k < 4; ++k) {
      int idx = tid + k * 512;
      if (idx < WCHUNKS) wreg[k] = ((const int4*)(ws + W2TG_OFF))[idx];
    }

    // X1 frags -> X1A[p][t]; re-zero X1A k-pad cols [112,128)
    if (tid < 256) {
      int row = tid >> 1, half = tid & 1;
      *(int4*)(smem + row * 272 + 224 + half * 16) = iz;
    }
#pragma unroll
    for (int h = 0; h < 2; ++h)
#pragma unroll
      for (int j = 0; j < 4; ++j) {
        if (j < NJ) {
          int t = (nh * 4 + j) * 16 + r;
          int p0 = (2 * mp + h) * 16 + quad * 4;
#pragma unroll
          for (int c = 0; c < 4; ++c)
            X1A[(p0 + c) * ST1 + t] = (short)f2bf(x1[h][j][c]);
        }
      }
    __syncthreads();  // (c) X1A ready

    // GEMM2: E = X1@W  (A=X1A[p][t] hoisted frags, B=Wbuf=Wt[s][t], K=t 4)
    short8 af[2][4];
#pragma unroll
    for (int h = 0; h < 2; ++h)
#pragma unroll
      for (int ks = 0; ks < 4; ++ks)
        af[h][ks] = *(const short8*)&X1A[((2 * mp + h) * 16 + r) * ST1 + ks * 32 + quad * 8];
#pragma unroll
    for (int j = 0; j < 4; ++j) {
      if (j < NJ) {
        int n = nh * 4 + j;
        floatx4 e0 = zed, e1 = zed;
#pragma unroll
        for (int ks = 0; ks < 4; ++ks) {
          short8 bf = *(const short8*)&Wbuf[(n * 16 + r) * ST1 + ks * 32 + quad * 8];
          e0 = __builtin_amdgcn_mfma_f32_16x16x32_bf16(af[0][ks], bf, e0, 0, 0, 0);
          e1 = __builtin_amdgcn_mfma_f32_16x16x32_bf16(af[1][ks], bf, e1, 0, 0, 0);
        }
        // gate in place: tem = x1 * (oma + alpha*exp(E)/S); pads -> x1=0
#pragma unroll
        for (int c = 0; c < 4; ++c) {
          x1[0][j][c] = x1[0][j][c] * (oma + __expf(e0[c]) * sinv[0][j][c]);
          x1[1][j][c] = x1[1][j][c] * (oma + __expf(e1[c]) * sinv[1][j][c]);
        }
      }
    }
    __syncthreads();  // (d) Wbuf(Wt) + X1A reads retired

    // tem frags -> X1A (same positions); Wbuf <- W2t from regs
#pragma unroll
    for (int h = 0; h < 2; ++h)
#pragma unroll
      for (int j = 0; j < 4; ++j) {
        if (j < NJ) {
          int t = (nh * 4 + j) * 16 + r;
          int p0 = (2 * mp + h) * 16 + quad * 4;
#pragma unroll
          for (int c = 0; c < 4; ++c)
            X1A[(p0 + c) * ST1 + t] = (short)f2bf(x1[h][j][c]);
        }
      }
#pragma unroll
    for (int k = 0; k < 4; ++k) {
      int idx = tid + k * 512;
      if (idx < WCHUNKS) ((int4*)Wbuf)[idx] = wreg[k];
    }
    __syncthreads();  // (e) temA + Wbuf(W2t) ready

    // issue Wt -> regs for next batch (consumed in phase f, lands under GEMM3)
    if (pf) {
#pragma unroll
      for (int k = 0; k < 4; ++k) {
        int idx = tid + k * 512;
        if (idx < WCHUNKS) wreg[k] = ((const int4*)(ws + WTG_OFF))[idx];
      }
    }

    // GEMM3: Y = tem@W2 + bias  (A=temA hoisted frags, B=Wbuf=W2t[q][t])
#pragma unroll
    for (int h = 0; h < 2; ++h)
#pragma unroll
      for (int ks = 0; ks < 4; ++ks)
        af[h][ks] = *(const short8*)&X1A[((2 * mp + h) * 16 + r) * ST1 + ks * 32 + quad * 8];
    float* Yb = Y + (size_t)(b0 + i) * 12000;
#pragma unroll
    for (int j = 0; j < 4; ++j) {
      if (j < NJ) {
        int n = nh * 4 + j;
        floatx4 y0 = br[0][j], y1 = br[1][j];
#pragma unroll
        for (int ks = 0; ks < 4; ++ks) {
          short8 bf = *(const short8*)&Wbuf[(n * 16 + r) * ST1 + ks * 32 + quad * 8];
          y0 = __builtin_amdgcn_mfma_f32_16x16x32_bf16(af[0][ks], bf, y0, 0, 0, 0);
          y1 = __builtin_amdgcn_mfma_f32_16x16x32_bf16(af[1][ks], bf, y1, 0, 0, 0);
        }
        int qc = n * 16 + r;
        if (qc < 100) {
          int p0 = (2 * mp) * 16 + quad * 4;      // h=0: p < 112 always
#pragma unroll
          for (int c = 0; c < 4; ++c) Yb[(p0 + c) * 100 + qc] = y0[c];
          int p1 = (2 * mp + 1) * 16 + quad * 4;  // h=1: guard p < 120
#pragma unroll
          for (int c = 0; c < 4; ++c)
            if (p1 + c < 120) Yb[(p1 + c) * 100 + qc] = y1[c];
        }
      }
    }
    __syncthreads();  // (f) Wbuf(W2t) + temA reads retired; region A free

    if (pf) {
      // stage Xt(i+1): pads + data (over temA head); Wbuf <- Wt from regs
      if (tid < 108) ((int4*)Xt)[900 + tid] = iz;
      for (int z = tid; z < 300; z += 512) {
        int t = z / 3, u = z - 3 * t;
        ((int4*)Xt)[t * 9 + 5 + u] = iz;
      }
#pragma unroll
      for (int k = 0; k < 2; ++k) {
        int idx = tid + k * 512;
        if (idx < 1000) {
          float4 v = xr[k];
          int e0 = idx * 4, d = e0 / 100, t0 = e0 - d * 100;
          Xt[(t0 + 0) * ST2 + d] = (short)f2bf(v.x);
          Xt[(t0 + 1) * ST2 + d] = (short)f2bf(v.y);
          Xt[(t0 + 2) * ST2 + d] = (short)f2bf(v.z);
          Xt[(t0 + 3) * ST2 + d] = (short)f2bf(v.w);
        }
      }
#pragma unroll
      for (int k = 0; k < 4; ++k) {
        int idx = tid + k * 512;
        if (idx < WCHUNKS) ((int4*)Wbuf)[idx] = wreg[k];
      }
    }
  }
}

extern "C" void kernel_launch(void* const* d_in, const int* in_sizes, int n_in,
                              void* d_out, int out_size, void* d_ws, size_t ws_size,
                              hipStream_t stream) {
  const float* X    = (const float*)d_in[0];
  const float* W1   = (const float*)d_in[1];
  const float* W    = (const float*)d_in[2];
  const float* al   = (const float*)d_in[3];
  const float* W2   = (const float*)d_in[4];
  const float* bias = (const float*)d_in[5];
  float* Y = (float*)d_out;
  char* ws = (char*)d_ws;

  hipMemsetAsync(ws, 0, WS_S_BYTES, stream);                 // S = 0
  int prep_elems = 112 * ST1 + 128 * ST2 + 112 * ST1;
  tabl_prep<<<(prep_elems + 255) / 256, 256, 0, stream>>>(W1, W, W2, ws);
  tabl_ph1<<<Bb / NB1, 256, 0, stream>>>(X, ws, (float*)ws);
  tabl_ph2<<<Bb / NB2, 512, 0, stream>>>(X, ws, al, bias, Y);
}